// Round 4
// baseline (184.228 us; speedup 1.0000x reference)
//
#include <hip/hip_runtime.h>
#include <math.h>

#define TSZ 64
#define USZ 8

// ws layout (floats): [0..511] w[u][s] (u-major, stride 64); [512..519] a[u]; [520..527] bb[u]

__global__ __launch_bounds__(1024) void setup_kernel(const float* __restrict__ alpha,
                             const float* __restrict__ beta,
                             const float* __restrict__ gamma_,
                             const float* __restrict__ tauZ,
                             const float* __restrict__ nZ,
                             const float* __restrict__ tauC,
                             const float* __restrict__ nC,
                             float* __restrict__ ws) {
    __shared__ float kbuf[2][USZ][TSZ];   // [0]=Kc, [1]=Kz_gamma
    __shared__ float kz[USZ][TSZ];
    __shared__ int ti_s[USZ];

    const int tid = threadIdx.x;          // 0..1023
    {
        // one gamma_filter evaluation per thread
        const int fid = tid >> 9;         // 0: Kc, 1: Kz-part
        const int rem = tid & 511;
        const int u   = rem >> 6;
        const int t   = rem & 63;
        const float tf = (float)t;
        float tau, n;
        if (fid == 0) { tau = tauC[u] * 100.0f; n = nC[u] * 10.0f; }
        else          { tau = tauZ[u] * 100.0f; n = nZ[u] * 10.0f; }
        float f = powf(tf, n) * expf(-tf / tau) / powf(tau, n + 1.0f) / tgammaf(n + 1.0f);
        kbuf[fid][u][t] = f;
    }
    __syncthreads();
    if (tid < 512) {
        const int u = tid >> 6;
        const int t = tid & 63;
        float g = gamma_[u] * 10.0f;
        kz[u][t] = g * kbuf[0][u][t] + (1.0f - g) * kbuf[1][u][t];
    }
    __syncthreads();
    if (tid < USZ) {
        const int u = tid;
        float best = kz[u][0];
        int bi = 0;
        for (int s = 1; s < TSZ; ++s) {
            float v = kz[u][s];
            if (v > best) { best = v; bi = s; }   // strict > => first-occurrence argmax (np semantics)
        }
        int ti = TSZ - bi;                         // T - z_shift
        if (ti > TSZ - 1) ti = TSZ - 1;
        if (ti < 0) ti = 0;
        ti_s[u] = ti;
        ws[512 + u] = alpha[u] * 100.0f;           // a
        ws[520 + u] = beta[u]  * 10.0f;            // bb
    }
    __syncthreads();
    if (tid < 512) {
        const int u = tid >> 6;
        const int t = tid & 63;
        int ti = ti_s[u];
        ws[u * TSZ + t] = (t <= ti) ? kz[u][ti - t] : 0.0f;
    }
}

// Wave-autonomous main: no LDS, no barriers. One wave handles one batch per
// grid-stride iteration; weights live in VGPRs; dot via butterfly shuffles.
__global__ __launch_bounds__(256) void main_kernel(const float* __restrict__ x,
                                                   const float* __restrict__ ws,
                                                   float* __restrict__ out,
                                                   int nbatch) {
    const int lane = threadIdx.x & 63;
    const int wid  = (blockIdx.x << 2) | (threadIdx.x >> 6);   // global wave id
    const int nwaves = gridDim.x << 2;

    // Per-lane weights: lane t holds w[u][t] for all 8 channels.
    float wreg[USZ], av[USZ], bv[USZ];
    #pragma unroll
    for (int u = 0; u < USZ; ++u) {
        wreg[u] = ws[u * TSZ + lane];   // coalesced
        av[u]   = ws[512 + u];          // uniform broadcast
        bv[u]   = ws[520 + u];
    }

    int b = wid;
    float xv = x[(size_t)b * TSZ + lane];           // first load
    for (; b < nbatch; ) {
        int bn = b + nwaves;
        float xn = 0.0f;
        if (bn < nbatch) xn = x[(size_t)bn * TSZ + lane];   // prefetch next

        float f[USZ];
        #pragma unroll
        for (int u = 0; u < USZ; ++u) {
            float p = xv * wreg[u];
            #pragma unroll
            for (int m = 1; m < 64; m <<= 1) p += __shfl_xor(p, m);
            f[u] = av[u] / (1.0f + bv[u] * p);
        }

        float4* o4 = (float4*)(out + (size_t)b * (TSZ * USZ) + lane * USZ);
        float4 lo, hi;
        lo.x = xv * f[0]; lo.y = xv * f[1]; lo.z = xv * f[2]; lo.w = xv * f[3];
        hi.x = xv * f[4]; hi.y = xv * f[5]; hi.z = xv * f[6]; hi.w = xv * f[7];
        o4[0] = lo;
        o4[1] = hi;

        b = bn;
        xv = xn;
    }
}

extern "C" void kernel_launch(void* const* d_in, const int* in_sizes, int n_in,
                              void* d_out, int out_size, void* d_ws, size_t ws_size,
                              hipStream_t stream) {
    const float* inputs = (const float*)d_in[0];
    const float* alpha  = (const float*)d_in[1];
    const float* beta   = (const float*)d_in[2];
    const float* gamma_ = (const float*)d_in[3];
    // d_in[4] zeta, d_in[5] tauY, d_in[6] nY: unused by reference
    const float* tauZ   = (const float*)d_in[7];
    const float* nZ     = (const float*)d_in[8];
    const float* tauC   = (const float*)d_in[9];
    const float* nC     = (const float*)d_in[10];
    float* out = (float*)d_out;
    float* ws  = (float*)d_ws;

    setup_kernel<<<1, 1024, 0, stream>>>(alpha, beta, gamma_, tauZ, nZ, tauC, nC, ws);

    const int nbatch = in_sizes[0] / TSZ;           // 65536
    // 2048 blocks x 4 waves = 8192 waves -> 8 batches per wave
    main_kernel<<<2048, 256, 0, stream>>>(inputs, ws, out, nbatch);
}

// Round 5
// 171.303 us; speedup vs baseline: 1.0754x; 1.0754x over previous
//
#include <hip/hip_runtime.h>
#include <math.h>

#define TSZ 64
#define USZ 8
#define NB  8           // batches per block in main kernel (small => many block generations overlap)
#define XS  68          // padded LDS row stride (floats); 68*4=272 B; dot-phase b128 reads conflict-free

typedef float nfloat4 __attribute__((ext_vector_type(4)));   // native vec for NT store

// ws layout (floats): [0..511] w[u][s] (u-major, stride 64); [512..519] a[u]; [520..527] bb[u]

__global__ __launch_bounds__(1024) void setup_kernel(const float* __restrict__ alpha,
                             const float* __restrict__ beta,
                             const float* __restrict__ gamma_,
                             const float* __restrict__ tauZ,
                             const float* __restrict__ nZ,
                             const float* __restrict__ tauC,
                             const float* __restrict__ nC,
                             float* __restrict__ ws) {
    __shared__ float kbuf[2][USZ][TSZ];   // [0]=Kc, [1]=Kz_gamma
    __shared__ float kz[USZ][TSZ];
    __shared__ int ti_s[USZ];

    const int tid = threadIdx.x;          // 0..1023
    {
        // one gamma_filter evaluation per thread
        const int fid = tid >> 9;         // 0: Kc, 1: Kz-part
        const int rem = tid & 511;
        const int u   = rem >> 6;
        const int t   = rem & 63;
        const float tf = (float)t;
        float tau, n;
        if (fid == 0) { tau = tauC[u] * 100.0f; n = nC[u] * 10.0f; }
        else          { tau = tauZ[u] * 100.0f; n = nZ[u] * 10.0f; }
        float f = powf(tf, n) * expf(-tf / tau) / powf(tau, n + 1.0f) / tgammaf(n + 1.0f);
        kbuf[fid][u][t] = f;
    }
    __syncthreads();
    if (tid < 512) {
        const int u = tid >> 6;
        const int t = tid & 63;
        float g = gamma_[u] * 10.0f;
        kz[u][t] = g * kbuf[0][u][t] + (1.0f - g) * kbuf[1][u][t];
    }
    __syncthreads();
    if (tid < USZ) {
        const int u = tid;
        float best = kz[u][0];
        int bi = 0;
        for (int s = 1; s < TSZ; ++s) {
            float v = kz[u][s];
            if (v > best) { best = v; bi = s; }   // strict > => first-occurrence argmax (np semantics)
        }
        int ti = TSZ - bi;                         // T - z_shift
        if (ti > TSZ - 1) ti = TSZ - 1;
        if (ti < 0) ti = 0;
        ti_s[u] = ti;
        ws[512 + u] = alpha[u] * 100.0f;           // a
        ws[520 + u] = beta[u]  * 10.0f;            // bb
    }
    __syncthreads();
    if (tid < 512) {
        const int u = tid >> 6;
        const int t = tid & 63;
        int ti = ti_s[u];
        ws[u * TSZ + t] = (t <= ti) ? kz[u][ti - t] : 0.0f;
    }
}

__global__ __launch_bounds__(256) void main_kernel(const float* __restrict__ x,
                                                   const float* __restrict__ ws,
                                                   float* __restrict__ out) {
    __shared__ __attribute__((aligned(16))) float xs[NB * XS];   // x tile, padded rows
    __shared__ __attribute__((aligned(16))) float wl[USZ * XS];  // weights, padded rows
    __shared__ __attribute__((aligned(16))) float fs[NB * USZ];  // per-(b,u) scale

    const int tid = threadIdx.x;
    const int blk = blockIdx.x;

    if (tid < 128) {
        // Stage w (512 floats = 128 float4) into padded LDS
        float4 v = ((const float4*)ws)[tid];
        int u  = tid >> 4;            // 16 float4 per row of 64
        int s0 = (tid & 15) << 2;
        *((float4*)&wl[u * XS + s0]) = v;
    } else {
        // Stage x tile (8 rows x 64 floats = 128 float4), coalesced
        int j = tid - 128;
        const float4* x4 = (const float4*)(x + (size_t)blk * NB * TSZ);
        float4 v = x4[j];
        int bl = j >> 4;
        int s0 = (j & 15) << 2;
        *((float4*)&xs[bl * XS + s0]) = v;
    }
    __syncthreads();

    // One thread per (b_local, u): 64-tap dot product from LDS (64 threads active)
    if (tid < NB * USZ) {
        const int bl = tid >> 3;
        const int u  = tid & 7;
        const float4* xr = (const float4*)&xs[bl * XS];
        const float4* wr = (const float4*)&wl[u * XS];
        float acc = 0.0f;
        #pragma unroll
        for (int j = 0; j < 16; ++j) {
            float4 a = xr[j];
            float4 b = wr[j];
            acc += a.x * b.x + a.y * b.y + a.z * b.z + a.w * b.w;
        }
        float av = ws[512 + u];
        float bv = ws[520 + u];
        fs[bl * USZ + u] = av / (1.0f + bv * acc);
    }
    __syncthreads();

    // Stream the 8*512 = 4096-float output tile, fully coalesced float4, non-temporal
    nfloat4* o4 = (nfloat4*)(out + (size_t)blk * NB * TSZ * USZ);
    #pragma unroll
    for (int k = 0; k < 4; ++k) {
        int j = tid + k * 256;        // float4 idx within block tile, 0..1023
        int bl   = j >> 7;            // 128 float4 per batch row
        int r    = j & 127;
        int t    = r >> 1;
        int half = r & 1;
        float xv = xs[bl * XS + t];
        float4 f = *((const float4*)&fs[bl * USZ + half * 4]);
        nfloat4 o;
        o.x = xv * f.x; o.y = xv * f.y; o.z = xv * f.z; o.w = xv * f.w;
        __builtin_nontemporal_store(o, &o4[j]);
    }
}

extern "C" void kernel_launch(void* const* d_in, const int* in_sizes, int n_in,
                              void* d_out, int out_size, void* d_ws, size_t ws_size,
                              hipStream_t stream) {
    const float* inputs = (const float*)d_in[0];
    const float* alpha  = (const float*)d_in[1];
    const float* beta   = (const float*)d_in[2];
    const float* gamma_ = (const float*)d_in[3];
    // d_in[4] zeta, d_in[5] tauY, d_in[6] nY: unused by reference
    const float* tauZ   = (const float*)d_in[7];
    const float* nZ     = (const float*)d_in[8];
    const float* tauC   = (const float*)d_in[9];
    const float* nC     = (const float*)d_in[10];
    float* out = (float*)d_out;
    float* ws  = (float*)d_ws;

    setup_kernel<<<1, 1024, 0, stream>>>(alpha, beta, gamma_, tauZ, nZ, tauC, nC, ws);

    const int nbatch = in_sizes[0] / TSZ;           // 65536
    main_kernel<<<nbatch / NB, 256, 0, stream>>>(inputs, ws, out);
}